// Round 4
// baseline (733.363 us; speedup 1.0000x reference)
//
#include <hip/hip_runtime.h>

// ---------------- problem constants ----------------
constexpr int BB = 1024;      // batch
constexpr int DD = 2048;      // feature dim
constexpr int NN = 16384;     // memory entries
constexpr float TEMP   = 0.05f;
constexpr float LAMBDA2 = 0.5f;
constexpr float MU      = 1.0f;
constexpr float EPSN    = 1e-12f;

typedef __bf16  bf16x8  __attribute__((ext_vector_type(8)));
typedef unsigned short ushort8 __attribute__((ext_vector_type(8)));
typedef float   floatx4 __attribute__((ext_vector_type(4)));

constexpr size_t F_SET   = (size_t)NN * DD;   // feature elems per set
constexpr size_t X_SET   = (size_t)BB * DD;   // xb elems per set
constexpr size_t SIM_SET = (size_t)BB * NN;   // sim elems per set

__device__ inline unsigned short f32_to_bf16(float f) {
  unsigned int u = __builtin_bit_cast(unsigned int, f);
  u += 0x7fffu + ((u >> 16) & 1u);      // round-to-nearest-even
  return (unsigned short)(u >> 16);
}

__device__ inline float block_sum256(float v, float* sbuf) {
#pragma unroll
  for (int o = 32; o > 0; o >>= 1) v += __shfl_down(v, o, 64);
  int lane = threadIdx.x & 63, w = threadIdx.x >> 6;
  __syncthreads();
  if (lane == 0) sbuf[w] = v;
  __syncthreads();
  return sbuf[0] + sbuf[1] + sbuf[2] + sbuf[3];
}

__device__ inline float block_max256(float v, float* sbuf) {
#pragma unroll
  for (int o = 32; o > 0; o >>= 1) v = fmaxf(v, __shfl_down(v, o, 64));
  int lane = threadIdx.x & 63, w = threadIdx.x >> 6;
  __syncthreads();
  if (lane == 0) sbuf[w] = v;
  __syncthreads();
  return fmaxf(fmaxf(sbuf[0], sbuf[1]), fmaxf(sbuf[2], sbuf[3]));
}

// ---------------- K1: row-l2norm of student -> bf16, MSE vs normalized teacher ----
// Batched over 3 sets: s = blockIdx.x/BB selects input pointers and output slots.
// Fallback (grid=BB): s==0, pass identical pointers in all 3 slots.
__global__ void __launch_bounds__(256) norm_mse_all(
    const float* __restrict__ X0, const float* __restrict__ X1, const float* __restrict__ X2,
    const float* __restrict__ T0, const float* __restrict__ T1, const float* __restrict__ T2,
    unsigned short* __restrict__ Xb, float* __restrict__ mse_part) {
  __shared__ float sbuf[4];
  const int s = blockIdx.x >> 10;              // /BB
  const int b = blockIdx.x & (BB - 1);
  const float* X = (s == 0) ? X0 : ((s == 1) ? X1 : X2);
  const float* T = (s == 0) ? T0 : ((s == 1) ? T1 : T2);
  unsigned short* xbp = Xb + (size_t)s * X_SET;
  const float4* xr = (const float4*)(X + (size_t)b * DD);
  const float4* tr = (const float4*)(T + (size_t)b * DD);
  float4 xv[2], tv[2];
  float sx = 0.f, st = 0.f;
#pragma unroll
  for (int i = 0; i < 2; ++i) {
    int idx = i * 256 + threadIdx.x;      // DD/4 = 512
    xv[i] = xr[idx];  tv[i] = tr[idx];
    sx += xv[i].x*xv[i].x + xv[i].y*xv[i].y + xv[i].z*xv[i].z + xv[i].w*xv[i].w;
    st += tv[i].x*tv[i].x + tv[i].y*tv[i].y + tv[i].z*tv[i].z + tv[i].w*tv[i].w;
  }
  sx = block_sum256(sx, sbuf);
  st = block_sum256(st, sbuf);
  const float rx = 1.f / fmaxf(sqrtf(sx), EPSN);
  const float rt = 1.f / fmaxf(sqrtf(st), EPSN);
  float ms = 0.f;
  ushort4* xb4 = (ushort4*)(xbp + (size_t)b * DD);
#pragma unroll
  for (int i = 0; i < 2; ++i) {
    int idx = i * 256 + threadIdx.x;
    float xn, tn, d;
    ushort4 o;
    xn = xv[i].x * rx; tn = tv[i].x * rt; d = xn - tn; ms += d * d; o.x = f32_to_bf16(xn);
    xn = xv[i].y * rx; tn = tv[i].y * rt; d = xn - tn; ms += d * d; o.y = f32_to_bf16(xn);
    xn = xv[i].z * rx; tn = tv[i].z * rt; d = xn - tn; ms += d * d; o.z = f32_to_bf16(xn);
    xn = xv[i].w * rx; tn = tv[i].w * rt; d = xn - tn; ms += d * d; o.w = f32_to_bf16(xn);
    xb4[idx] = o;
  }
  ms = block_sum256(ms, sbuf);
  if (threadIdx.x == 0) mse_part[s * BB + b] = ms;
}

// ---------------- K2: features fp32 -> bf16, batched streaming convert -----------
// Batched: 4096 blocks per set, s = blockIdx.x/4096. Fallback grid=4096 -> s==0.
__global__ void __launch_bounds__(256) feat_convert_all(
    const float* __restrict__ F0, const float* __restrict__ F1, const float* __restrict__ F2,
    unsigned short* __restrict__ Fb) {
  const int s  = blockIdx.x >> 12;
  const int lb = blockIdx.x & 4095;
  const float* F = (s == 0) ? F0 : ((s == 1) ? F1 : F2);
  unsigned short* fb = Fb + (size_t)s * F_SET;
  const float4* fr = (const float4*)F;
  constexpr int TOT = NN * DD / 8;            // ushort8 chunks per set
  constexpr int STRIDE = 4096 * 256;
  for (int i = lb * 256 + threadIdx.x; i < TOT; i += STRIDE) {
    float4 a = fr[i * 2], b = fr[i * 2 + 1];
    ushort8 o;
    o[0] = f32_to_bf16(a.x); o[1] = f32_to_bf16(a.y);
    o[2] = f32_to_bf16(a.z); o[3] = f32_to_bf16(a.w);
    o[4] = f32_to_bf16(b.x); o[5] = f32_to_bf16(b.y);
    o[6] = f32_to_bf16(b.z); o[7] = f32_to_bf16(b.w);
    *(ushort8*)(fb + (size_t)i * 8) = o;
  }
}

// ---------------- K3: bf16 MFMA GEMM  sim[M,N] = A[M,K] * Bm[N,K]^T ---------------
// 256x256 tile, BK=64, 8 waves (2Mx4N), double-buffered LDS (128 KiB).
// Round-3 schedule kept verbatim: compile-time buffer indices (h unrolled) +
// counted vmcnt(4) once per K-tile (never 0) + per-phase barrier/lgkmcnt/setprio.
// Round-4: batched over sets via blockIdx.z (set strides on internal ws buffers).
constexpr int BM = 256, BN = 256, BK = 64;
constexpr int KT = DD / BK;                  // 32 K-tiles

__device__ inline void async_copy16(const void* g, void* l) {
  __builtin_amdgcn_global_load_lds(
      (const __attribute__((address_space(1))) unsigned int*)g,
      (__attribute__((address_space(3))) unsigned int*)l, 16, 0, 0);
}

// stage one 128x64 half-tile (16 KB): 2 global_load_lds x 512 threads x 16 B
__device__ __forceinline__ void stage_half(const unsigned short* src,
                                           unsigned short* dstRegion, int tid8) {
  async_copy16(src, dstRegion + tid8);                    // rows 0..63
  async_copy16(src + 64 * DD, dstRegion + 4096 + tid8);   // rows 64..127
}

__global__ void __launch_bounds__(512, 2) gemm_all(
    const unsigned short* __restrict__ Ab,   // [3][M][K] bf16 bits (normalized x)
    const unsigned short* __restrict__ Fb,   // [3][N][K] bf16 bits (features)
    float* __restrict__ Csim) {              // [3][M][N] fp32 sim
  __shared__ __align__(16) unsigned short As[2 * 2 * 128 * 64];   // 64 KB
  __shared__ __align__(16) unsigned short Bs[2 * 2 * 128 * 64];   // 64 KB

  const int set = blockIdx.z;
  const unsigned short* A  = Ab + (size_t)set * X_SET;
  const unsigned short* Bm = Fb + (size_t)set * F_SET;
  float* C = Csim + (size_t)set * SIM_SET;

  const int tid  = threadIdx.x;
  const int lane = tid & 63;
  const int wave = tid >> 6;      // 0..7
  const int l16  = lane & 15;
  const int quad = lane >> 4;
  const int rm   = wave >> 2;     // 0..1 : wave row-group (A half)
  const int rn   = wave & 3;      // 0..3 : wave col-group
  const int m0 = blockIdx.y * BM;
  const int n0 = blockIdx.x * BN;

  // ds_read chunk offsets: logical chunk (s*4+quad) xor'd by row&7 (=l16&7)
  const int xr = l16 & 7;
  const int cs[2] = { (quad ^ xr) * 8, ((4 + quad) ^ xr) * 8 };

  // staging geometry: thread covers linear LDS bytes tid*16 (+8192 B for inst1);
  // physical chunk pc = tid&7 holds logical chunk pc^(row&7) -> pre-swizzled source
  const int srow = tid >> 3;                                  // 0..63
  const int lcol = ((tid & 7) ^ (srow & 7)) * 8;              // source col (elems)
  const int tid8 = tid * 8;
  const unsigned short* aSrcT = A  + (size_t)(m0 + srow) * DD + lcol;
  const unsigned short* bSrcT = Bm + (size_t)(n0 + srow) * DD + lcol;

  floatx4 acc[8][4] = {};

  // ---- prologue: A(0)->As0, B(0)->Bs0, B(1)->Bs1; wait A(0)+B(0) ----
  stage_half(aSrcT,                 As,         tid8);
  stage_half(aSrcT + 128 * DD,      As + 8192,  tid8);
  stage_half(bSrcT,                 Bs,         tid8);
  stage_half(bSrcT + 128 * DD,      Bs + 8192,  tid8);
  stage_half(bSrcT + BK,            Bs + 16384, tid8);
  stage_half(bSrcT + 128 * DD + BK, Bs + 24576, tid8);
  asm volatile("s_waitcnt vmcnt(4)" ::: "memory");   // leaves B(1) in flight
  asm volatile("s_barrier" ::: "memory");

  for (int i = 0; i < KT / 2; ++i) {
#pragma unroll
    for (int h = 0; h < 2; ++h) {          // fully unrolled: h is a constant
      const int t = 2 * i + h;
      unsigned short* Adst = As + (h ^ 1) * 16384;   // A(t+1) -> other buffer
      unsigned short* Bdst = Bs + h * 16384;         // B(t+2) -> own buffer
      const int kA = (t + 1 < KT) ? (t + 1) * BK : 0;   // tail clamp: junk loads
      const int kB = (t + 2 < KT) ? (t + 2) * BK : 0;   // into dead regions
      const unsigned short* aS = aSrcT + kA;
      const unsigned short* bS = bSrcT + kB;
      const unsigned short* aB = As + h * 16384 + rm * 8192 + l16 * 64;
      const unsigned short* bB = Bs + h * 16384 + rn * 4096 + l16 * 64;

      bf16x8 bf[4][2];
#pragma unroll
      for (int mp = 0; mp < 4; ++mp) {     // 4 phases per K-tile
        if (mp == 0) {
#pragma unroll
          for (int n = 0; n < 4; ++n)
#pragma unroll
            for (int s = 0; s < 2; ++s)
              bf[n][s] = __builtin_bit_cast(bf16x8,
                           *(const ushort8*)(bB + n * 1024 + cs[s]));
        }
        bf16x8 af[2][2];
#pragma unroll
        for (int mi = 0; mi < 2; ++mi)
#pragma unroll
          for (int s = 0; s < 2; ++s)
            af[mi][s] = __builtin_bit_cast(bf16x8,
                          *(const ushort8*)(aB + (mp * 2 + mi) * 1024 + cs[s]));

        // one half-tile prefetch per phase (stays in flight across barriers)
        if      (mp == 0) stage_half(aS,            Adst,        tid8);
        else if (mp == 1) stage_half(aS + 128 * DD, Adst + 8192, tid8);
        else if (mp == 2) stage_half(bS,            Bdst,        tid8);
        else              stage_half(bS + 128 * DD, Bdst + 8192, tid8);

        asm volatile("s_barrier" ::: "memory");
        asm volatile("s_waitcnt lgkmcnt(0)" ::: "memory");
        __builtin_amdgcn_s_setprio(1);
#pragma unroll
        for (int mi = 0; mi < 2; ++mi)
#pragma unroll
          for (int n = 0; n < 4; ++n)
#pragma unroll
            for (int s = 0; s < 2; ++s)
              acc[mp * 2 + mi][n] = __builtin_amdgcn_mfma_f32_16x16x32_bf16(
                  af[mi][s], bf[n][s], acc[mp * 2 + mi][n], 0, 0, 0);
        __builtin_amdgcn_s_setprio(0);
        if (mp == 3)   // counted wait ONCE per K-tile; never drain to 0
          asm volatile("s_waitcnt vmcnt(4)" ::: "memory");
        asm volatile("s_barrier" ::: "memory");
      }
    }
  }

  // epilogue: C/D layout col = lane&15, row = quad*4 + reg  [m89/m91-verified]
#pragma unroll
  for (int r = 0; r < 8; ++r) {
    const int grow = m0 + rm * 128 + r * 16 + quad * 4;
#pragma unroll
    for (int n = 0; n < 4; ++n) {
      const int gcol = n0 + rn * 64 + n * 16 + l16;
#pragma unroll
      for (int i = 0; i < 4; ++i)
        C[(size_t)(grow + i) * NN + gcol] = acc[r][n][i];
    }
  }
}

// ---------------- K4: per-row CE terms from sim, single memory pass ----------------
// Batched: s = blockIdx.x/BB. Fallback grid=BB -> s==0, pass offset cep.
__global__ void __launch_bounds__(256) rowstat_all(
    const float* __restrict__ sim, const int* __restrict__ tgt,
    float* __restrict__ ce_part) {
  __shared__ float sbuf[4];
  const int s = blockIdx.x >> 10;              // /BB
  const int b = blockIdx.x & (BB - 1);
  const float* simp = sim + (size_t)s * SIM_SET;
  const float4* sr = (const float4*)(simp + (size_t)b * NN);
  constexpr float INV_T = 1.0f / TEMP;

  float4 dv[16];                       // 64 VGPRs of distances
  float m1 = -1e30f, s1 = 0.f;         // running LSE state for sim*INV_T
  float m2 = -1e30f;
#pragma unroll
  for (int i = 0; i < 16; ++i) {
    const int idx = i * 256 + threadIdx.x;   // NN/4 = 4096 float4s
    float4 sv = sr[idx];
    float lm = fmaxf(fmaxf(sv.x, sv.y), fmaxf(sv.z, sv.w)) * INV_T;
    if (lm > m1) { s1 *= expf(m1 - lm); m1 = lm; }
    s1 += expf(sv.x * INV_T - m1) + expf(sv.y * INV_T - m1)
        + expf(sv.z * INV_T - m1) + expf(sv.w * INV_T - m1);
    float4 d;
    d.x = sqrtf(fmaxf(2.f - 2.f * sv.x, 0.f));
    d.y = sqrtf(fmaxf(2.f - 2.f * sv.y, 0.f));
    d.z = sqrtf(fmaxf(2.f - 2.f * sv.z, 0.f));
    d.w = sqrtf(fmaxf(2.f - 2.f * sv.w, 0.f));
    dv[i] = d;
    m2 = fmaxf(m2, fmaxf(fmaxf(d.x, d.y), fmaxf(d.z, d.w)));
  }
  const float M1 = block_max256(m1, sbuf);
  const float s1t = block_sum256(s1 * expf(m1 - M1), sbuf);
  const float M2 = block_max256(m2, sbuf);

  float s2 = 0.f;
#pragma unroll
  for (int i = 0; i < 16; ++i) {
    float4 d = dv[i];
    s2 += expf(d.x - M2) + expf(d.y - M2) + expf(d.z - M2) + expf(d.w - M2);
  }
  const float s2t = block_sum256(s2, sbuf);
  const float invs2 = 1.f / s2t;

  float sp = 0.f;
#pragma unroll
  for (int i = 0; i < 16; ++i) {
    float4 d = dv[i];
    sp += expf(expf(d.x - M2) * invs2) + expf(expf(d.y - M2) * invs2)
        + expf(expf(d.z - M2) * invs2) + expf(expf(d.w - M2) * invs2);
  }
  const float spt = block_sum256(sp, sbuf);

  if (threadIdx.x == 0) {
    const int t = tgt[b];
    const float st = simp[(size_t)b * NN + t];
    const float dt = sqrtf(fmaxf(2.f - 2.f * st, 0.f));
    const float pt = expf(dt - M2) * invs2;
    const float ce1 = M1 + logf(s1t) - st * INV_T;   // lse(sim/T) - sim_t/T
    const float ce2 = logf(spt) - pt;                // lse(p) - p_t
    ce_part[b] = ce1 + ce2;      // caller offsets by set (batched: below)
  }
}

// batched variant writes into cep[s*BB+b]; to keep one kernel, the batched path
// passes cep base and we offset here via s. (Fallback passes cep+i*BB, s==0.)
__global__ void __launch_bounds__(256) rowstat_all_batched(
    const float* __restrict__ sim, const int* __restrict__ tgt,
    float* __restrict__ ce_part) {
  // thin wrapper semantics folded into rowstat_all via pointer math is not
  // possible without an extra arg; simplest correct form: duplicate with offset.
  __shared__ float sbuf[4];
  const int s = blockIdx.x >> 10;
  const int b = blockIdx.x & (BB - 1);
  const float* simp = sim + (size_t)s * SIM_SET;
  const float4* sr = (const float4*)(simp + (size_t)b * NN);
  constexpr float INV_T = 1.0f / TEMP;
  float4 dv[16];
  float m1 = -1e30f, s1 = 0.f, m2 = -1e30f;
#pragma unroll
  for (int i = 0; i < 16; ++i) {
    const int idx = i * 256 + threadIdx.x;
    float4 sv = sr[idx];
    float lm = fmaxf(fmaxf(sv.x, sv.y), fmaxf(sv.z, sv.w)) * INV_T;
    if (lm > m1) { s1 *= expf(m1 - lm); m1 = lm; }
    s1 += expf(sv.x * INV_T - m1) + expf(sv.y * INV_T - m1)
        + expf(sv.z * INV_T - m1) + expf(sv.w * INV_T - m1);
    float4 d;
    d.x = sqrtf(fmaxf(2.f - 2.f * sv.x, 0.f));
    d.y = sqrtf(fmaxf(2.f - 2.f * sv.y, 0.f));
    d.z = sqrtf(fmaxf(2.f - 2.f * sv.z, 0.f));
    d.w = sqrtf(fmaxf(2.f - 2.f * sv.w, 0.f));
    dv[i] = d;
    m2 = fmaxf(m2, fmaxf(fmaxf(d.x, d.y), fmaxf(d.z, d.w)));
  }
  const float M1 = block_max256(m1, sbuf);
  const float s1t = block_sum256(s1 * expf(m1 - M1), sbuf);
  const float M2 = block_max256(m2, sbuf);
  float s2 = 0.f;
#pragma unroll
  for (int i = 0; i < 16; ++i) {
    float4 d = dv[i];
    s2 += expf(d.x - M2) + expf(d.y - M2) + expf(d.z - M2) + expf(d.w - M2);
  }
  const float s2t = block_sum256(s2, sbuf);
  const float invs2 = 1.f / s2t;
  float sp = 0.f;
#pragma unroll
  for (int i = 0; i < 16; ++i) {
    float4 d = dv[i];
    sp += expf(expf(d.x - M2) * invs2) + expf(expf(d.y - M2) * invs2)
        + expf(expf(d.z - M2) * invs2) + expf(expf(d.w - M2) * invs2);
  }
  const float spt = block_sum256(sp, sbuf);
  if (threadIdx.x == 0) {
    const int t = tgt[b];
    const float st = simp[(size_t)b * NN + t];
    const float dt = sqrtf(fmaxf(2.f - 2.f * st, 0.f));
    const float pt = expf(dt - M2) * invs2;
    const float ce1 = M1 + logf(s1t) - st * INV_T;
    const float ce2 = logf(spt) - pt;
    ce_part[s * BB + b] = ce1 + ce2;
  }
}

// ---------------- K5: final weighted reduce of all partials -> d_out ----------------
__global__ void __launch_bounds__(256) final_reduce_kernel(
    const float* __restrict__ mse_part,   // [3*BB]
    const float* __restrict__ ce_part,    // [3*BB]
    float* __restrict__ loss) {
  __shared__ float sbuf[4];
  float s = 0.f;
  for (int i = threadIdx.x; i < 3 * BB; i += 256) {
    const float w = (i < BB) ? (1.0f - LAMBDA2) : LAMBDA2;
    s += w * (MU * mse_part[i] + ce_part[i]);
  }
  s = block_sum256(s, sbuf);
  if (threadIdx.x == 0) loss[0] = s * (1.0f / (float)BB);
}

// ---------------- launch ----------------
extern "C" void kernel_launch(void* const* d_in, const int* in_sizes, int n_in,
                              void* d_out, int out_size, void* d_ws, size_t ws_size,
                              hipStream_t stream) {
  const float* xin[3] = {(const float*)d_in[0], (const float*)d_in[1], (const float*)d_in[2]};
  const float* tin[3] = {(const float*)d_in[3], (const float*)d_in[4], (const float*)d_in[5]};
  const int*   targets = (const int*)d_in[6];
  const float* fin[3] = {(const float*)d_in[8], (const float*)d_in[9], (const float*)d_in[10]};

  char* ws = (char*)d_ws;
  const size_t needB = 3 * F_SET * 2 + 3 * SIM_SET * 4 + 3 * X_SET * 2
                     + 2 * (size_t)3 * BB * 4;           // ~396 MiB

  if (ws_size >= needB) {
    // -------- batched path: 5 dispatches total --------
    size_t off = 0;
    unsigned short* featb = (unsigned short*)(ws + off); off += 3 * F_SET * 2;   // 192 MiB
    float*          sim   = (float*)(ws + off);          off += 3 * SIM_SET * 4; // 192 MiB
    unsigned short* xb    = (unsigned short*)(ws + off); off += 3 * X_SET * 2;   //  12 MiB
    float*          msep  = (float*)(ws + off);          off += (size_t)3 * BB * 4;
    float*          cep   = (float*)(ws + off);          off += (size_t)3 * BB * 4;

    norm_mse_all<<<3 * BB, 256, 0, stream>>>(
        xin[0], xin[1], xin[2], tin[0], tin[1], tin[2], xb, msep);
    feat_convert_all<<<3 * 4096, 256, 0, stream>>>(fin[0], fin[1], fin[2], featb);
    gemm_all<<<dim3(NN / BN, BB / BM, 3), 512, 0, stream>>>(xb, featb, sim);
    rowstat_all_batched<<<3 * BB, 256, 0, stream>>>(sim, targets, cep);
    final_reduce_kernel<<<1, 256, 0, stream>>>(msep, cep, (float*)d_out);
  } else {
    // -------- fallback: sequential single-set buffers (old 14-dispatch path) ----
    size_t off = 0;
    unsigned short* featb = (unsigned short*)(ws + off); off += F_SET * 2;    // 64 MiB
    float*          sim   = (float*)(ws + off);          off += SIM_SET * 4;  // 64 MiB
    unsigned short* xb    = (unsigned short*)(ws + off); off += X_SET * 2;    //  4 MiB
    float*          msep  = (float*)(ws + off);          off += (size_t)3 * BB * 4;
    float*          cep   = (float*)(ws + off);          off += (size_t)3 * BB * 4;

    for (int i = 0; i < 3; ++i) {
      norm_mse_all<<<BB, 256, 0, stream>>>(
          xin[i], xin[i], xin[i], tin[i], tin[i], tin[i], xb, msep + i * BB);
      feat_convert_all<<<4096, 256, 0, stream>>>(fin[i], fin[i], fin[i], featb);
      gemm_all<<<dim3(NN / BN, BB / BM, 1), 512, 0, stream>>>(xb, featb, sim);
      rowstat_all<<<BB, 256, 0, stream>>>(sim, targets, cep + i * BB);
    }
    final_reduce_kernel<<<1, 256, 0, stream>>>(msep, cep, (float*)d_out);
  }
}